// Round 4
// baseline (86.822 us; speedup 1.0000x reference)
//
#include <hip/hip_runtime.h>

// KAN layer: out[b,o] = sum_i [ sum_g w[o,i,g]*exp(-|tanh(x[b,i])-grid[g]|*s[o,i])
//                               + ba[o,i]*tanh(x[b,i]) ]
// Factorization: exp(-s|xn-g|) = exp(-s*xn)*[w*e^{s*g}]   (g <= xn)
//                              = exp(+s*xn)*[w*e^{-s*g}]  (g >  xn)
// Prefix/suffix tables per (o,i) over the 5 possible split points k (xn in
// (-1,1) => k in [2,6]); per (b,o,i): 2 exp2 + 3 fma + one LDS-cached 8B read.

#define B_   256
#define OUT_ 256
#define IN_  256
#define G_   8
#define NK   5           // k' = k-2
#define BG   32          // b's per main block
#define ICH  16          // i's per chunk (split-K)
#define NIC  (IN_/ICH)   // 16 chunks
#define OT   64          // o-tile = one wave width

// ---------------------------------------------------------------------------
// Kernel 1 (prep), grid 256 x 256:
//  part A: idx=(b,i) i-fast  -> xn=tanh(x), split index k. Coalesced R/W.
//  part B: i=blockIdx, o=tid -> per-(o,i) tables; stores coalesced 512B/wave
//          (T layout [k'][i][o], o fast, matching main's slab loads).
// ---------------------------------------------------------------------------
__global__ __launch_bounds__(256) void kan_prep(
        const float* __restrict__ x,
        const float* __restrict__ w,
        const float* __restrict__ sc,
        const float* __restrict__ ba,
        const float* __restrict__ grid,
        float2* __restrict__ xnk,
        float2* __restrict__ sbt,
        float2* __restrict__ T)
{
    float g[G_];
#pragma unroll
    for (int j = 0; j < G_; ++j) g[j] = grid[j];   // uniform broadcast loads

    // ---- part A: one (b,i) per thread, i fast -> coalesced
    {
        const int idx = blockIdx.x * 256 + threadIdx.x;
        const float xn = tanhf(x[idx]);
        int k = 0;
#pragma unroll
        for (int j = 0; j < G_; ++j) k += (g[j] <= xn) ? 1 : 0;
        k = min(max(k, 2), 6) - 2;                 // 0..4
        xnk[idx] = make_float2(xn, (float)k);
    }

    // ---- part B: one i per block, o = tid -> all stores coalesced
    {
        const int i = blockIdx.x;
        const int o = threadIdx.x;
        const int base = o * IN_ + i;              // strided reads (small, L2)
        const float s  = sc[base];
        const float bv = ba[base];

        float Ep[G_], Em[G_];
#pragma unroll
        for (int j = 0; j < G_; ++j) {
            const float wv = w[base * G_ + j];
            const float t  = s * g[j];
            Ep[j] = wv * __expf(t);
            Em[j] = wv * __expf(-t);
        }
#pragma unroll
        for (int kk = 0; kk < NK; ++kk) {
            const int k = kk + 2;
            float A = 0.f, Bv = 0.f;
#pragma unroll
            for (int j = 0; j < G_; ++j) {
                if (j < k) A += Ep[j]; else Bv += Em[j];   // compile-time split
            }
            T[(kk * IN_ + i) * OUT_ + o] = make_float2(A, Bv);  // 512B/wave
        }
        sbt[i * OUT_ + o] = make_float2(s * 1.44269504088896340736f, bv);
    }
}

// ---------------------------------------------------------------------------
// Kernel 2 (main): grid = 64 slabs (4 o-tiles x 16 i-chunks) x 8 b-groups.
// Slab (T + sbt for this o-tile/i-chunk) cached in LDS once, reused for all
// 32 b's. Blocks sharing a slab are == mod 8 -> same XCD -> one L2 copy.
// Wave w handles 8 b's; per (b,i): 2 LDS reads, 2 exp2, 3 fma.
// ---------------------------------------------------------------------------
__global__ __launch_bounds__(256, 2) void kan_main(
        const float2* __restrict__ xnk,
        const float2* __restrict__ sbt,
        const float2* __restrict__ T,
        float* __restrict__ partial)
{
    const int lane = threadIdx.x & 63;
    const int w    = threadIdx.x >> 6;
    const int slab = blockIdx.x & 63;     // (ot, ic) — slab-sharers same XCD
    const int bg   = blockIdx.x >> 6;     // 0..7
    const int ot   = slab & 3;
    const int ic   = slab >> 2;
    const int o0   = ot * OT;
    const int i0   = ic * ICH;
    const int b0   = bg * BG;

    __shared__ float2 sT[NK * ICH * OT];  // 40 KB  [k][ii][o]
    __shared__ float2 sSB[ICH * OT];      // 8 KB   [ii][o] = (c, ba)
    __shared__ float2 sXK[BG * ICH];      // 4 KB   [bb][ii] = (xn, slab offset)

    for (int idx = threadIdx.x; idx < NK * ICH * OT; idx += 256) {
        const int kk = idx >> 10;         // /(ICH*OT)
        const int rem = idx & 1023;
        const int ii = rem >> 6, ol = rem & 63;
        sT[idx] = T[(kk * IN_ + i0 + ii) * OUT_ + o0 + ol];   // coalesced
    }
    for (int idx = threadIdx.x; idx < ICH * OT; idx += 256) {
        const int ii = idx >> 6, ol = idx & 63;
        sSB[idx] = sbt[(i0 + ii) * OUT_ + o0 + ol];           // coalesced
    }
    // BUG FIX (R3): BG*ICH = 512 > blockDim 256 — must stride, not mask.
    for (int idx = threadIdx.x; idx < BG * ICH; idx += 256) {
        const int bb = idx >> 4, ii = idx & 15;
        const float2 v = xnk[(b0 + bb) * IN_ + i0 + ii];
        sXK[idx] = make_float2(v.x, __int_as_float(((int)v.y) << 10));
    }
    __syncthreads();

    float acc[8];
#pragma unroll
    for (int bb = 0; bb < 8; ++bb) acc[bb] = 0.f;

    const int wb = w * 8;                 // this wave's first b (local)
    for (int ii = 0; ii < ICH; ++ii) {
        const float2 sb = sSB[ii * OT + lane];     // 2-way bank alias: free
        const int il = ii * OT + lane;
#pragma unroll
        for (int bb = 0; bb < 8; ++bb) {
            const float2 xk = sXK[(wb + bb) * ICH + ii];        // broadcast
            const float2 rec = sT[__float_as_int(xk.y) + il];   // k-slab read
            const float t = sb.x * xk.x;           // s*log2e*xn
            float a = fmaf(sb.y, xk.x, acc[bb]);   // + ba*xn
            a       = fmaf(exp2f(-t), rec.x, a);   // + e^{-s*xn} * A[k]
            acc[bb] = fmaf(exp2f(t),  rec.y, a);   // + e^{+s*xn} * B[k]
        }
    }

    float* p = partial + ((size_t)ic * B_ + b0 + wb) * OUT_ + o0 + lane;
#pragma unroll
    for (int bb = 0; bb < 8; ++bb) p[bb * OUT_] = acc[bb];      // coalesced
}

// ---------------------------------------------------------------------------
// Kernel 3: reduce the NIC=16 i-chunk partials. Fully overwrites d_out.
// ---------------------------------------------------------------------------
__global__ __launch_bounds__(256) void kan_reduce(
        const float* __restrict__ partial, float* __restrict__ out)
{
    const int idx = blockIdx.x * 256 + threadIdx.x;
    float s = 0.f;
#pragma unroll
    for (int c = 0; c < NIC; ++c) s += partial[c * (B_ * OUT_) + idx];
    out[idx] = s;
}

// ---------------------------------------------------------------------------
extern "C" void kernel_launch(void* const* d_in, const int* in_sizes, int n_in,
                              void* d_out, int out_size, void* d_ws, size_t ws_size,
                              hipStream_t stream)
{
    const float* x    = (const float*)d_in[0];
    const float* w    = (const float*)d_in[1];   // (OUT, IN, G)
    const float* sc   = (const float*)d_in[2];   // (OUT, IN)
    const float* ba   = (const float*)d_in[3];   // (OUT, IN)
    const float* grid = (const float*)d_in[4];   // (G)
    float* out = (float*)d_out;

    // ws: xnk 512KB | sbt 512KB | T 2.5MB | partial 4MB  (7.5 MB total)
    char* ws = (char*)d_ws;
    float2* xnk = (float2*)(ws);
    float2* sbt = (float2*)(ws + 512 * 1024);
    float2* T   = (float2*)(ws + 1024 * 1024);
    float*  partial = (float*)(ws + 1024 * 1024 + (size_t)NK * IN_ * OUT_ * sizeof(float2));

    kan_prep<<<IN_, 256, 0, stream>>>(x, w, sc, ba, grid, xnk, sbt, T);
    kan_main<<<64 * (B_ / BG), 256, 0, stream>>>(xnk, sbt, T, partial);
    kan_reduce<<<(B_ * OUT_) / 256, 256, 0, stream>>>(partial, out);
}